// Round 8
// baseline (3125.061 us; speedup 1.0000x reference)
//
#include <hip/hip_runtime.h>
#include <hip/hip_bf16.h>

// Sizes (fixed by the reference)
#define BN  256
#define SN  512
#define INN 64
#define HN  256
#define MN  64

// LDS strides (f16 elems unless noted)
#define ZINS 328   // zin: [x(64) | h(256)] + 8 pad
#define ZBS  264   // z0/z1: 256 + 8
#define CFS  72    // cfc: 64 + 8
#define HTS  36    // htmp row stride (f32)

// Output offsets (f32 elements)
#define OFF_ACT  393216
#define OFF_CONF 524288
#define OFF_HN   655360

#define FLAG_STRIDE 32        // u32 per flag slot (128 B line spacing)
#define FLAG_BYTES  16384     // 128 slots * 128 B  (same as R5)

typedef _Float16 h8 __attribute__((ext_vector_type(8)));
typedef float fx4 __attribute__((ext_vector_type(4)));
typedef unsigned long long u64;
union h4u { _Float16 h[4]; u64 u; };

__device__ __forceinline__ fx4 mfma16(h8 a, h8 b, fx4 c) {
    return __builtin_amdgcn_mfma_f32_16x16x32_f16(a, b, c, 0, 0, 0);
}
__device__ __forceinline__ float fast_tanh(float x) {
    float e = __expf(2.0f * x);
    return 1.0f - 2.0f / (e + 1.0f);
}
__device__ __forceinline__ float fast_sig(float x) { return 1.0f / (1.0f + __expf(-x)); }
__device__ __forceinline__ float lecun_tanh(float x) { return 1.7159f * fast_tanh(0.666f * x); }
__device__ __forceinline__ float softplus_f(float x) {
    return fmaxf(x, 0.0f) + __logf(1.0f + __expf(-fabsf(x)));
}

template <int NW>
__device__ __forceinline__ h8 loadB(const float* __restrict__ w, int col, int kbase) {
    h8 r;
#pragma unroll
    for (int j = 0; j < 8; ++j) r[j] = (_Float16)w[(kbase + j) * NW + col];
    return r;
}

__global__ void __launch_bounds__(1024, 1) lh_scan_kernel(
    const float* __restrict__ x, const float* __restrict__ tsp, const float* __restrict__ hx,
    const float* __restrict__ w0, const float* __restrict__ b0,
    const float* __restrict__ w1, const float* __restrict__ b1,
    const float* __restrict__ f1w, const float* __restrict__ f1b,
    const float* __restrict__ f2w, const float* __restrict__ f2b,
    const float* __restrict__ taw, const float* __restrict__ tab,
    const float* __restrict__ tbw, const float* __restrict__ tbb,
    const float* __restrict__ pw, const float* __restrict__ pbias,
    const float* __restrict__ ihw0, const float* __restrict__ ihb0,
    const float* __restrict__ ihw1, const float* __restrict__ ihb1,
    const float* __restrict__ ahw0, const float* __restrict__ ahb0,
    const float* __restrict__ ahw1, const float* __restrict__ ahb1,
    const float* __restrict__ chw0, const float* __restrict__ chb0,
    const float* __restrict__ chw1, const float* __restrict__ chb1,
    float* __restrict__ out, unsigned int* __restrict__ flags,
    u64* __restrict__ hbuf)
{
    __shared__ __align__(16) _Float16 zin[16 * ZINS];
    __shared__ __align__(16) _Float16 z0b[16 * ZBS];
    __shared__ __align__(16) _Float16 z1b[16 * ZBS];
    __shared__ __align__(16) _Float16 cfcb[16 * CFS];
    __shared__ __align__(16) _Float16 hdl[8 * 8 * 64 * 8];   // head B-frags: [unit][kk][lane][8]
    __shared__ __align__(16) _Float16 pfl[8 * 4 * 64 * 8];   // proj B-frags: [kk][u][lane][8]
    __shared__ __align__(16) float htmp[4 * 16 * HTS];
    __shared__ float hidI[16 * 16];
    __shared__ float hidA[16 * 16];
    __shared__ float hidC[16 * 8];
    __shared__ float tsb[2][16];
    __shared__ float wsm[80];

    const int tid  = threadIdx.x;
    const int wv   = tid >> 6;          // 0..15
    const int lane = tid & 63;
    const int lo   = lane & 15;
    const int hi   = lane >> 4;
    const int hi8  = hi * 8;

    const int bid   = blockIdx.x;
    const int xcd   = bid & 7;
    const int c     = (bid >> 3) & 7;   // column-slice id 0..7
    const int gsel  = bid >> 6;         // 0/1
    const int g     = xcd + 8 * gsel;   // batch group; 8 blocks share g (same XCD heuristic)
    const int bg    = g * 16;
    const int sbase = c * 32;           // this block's 32 head columns

    // ---- small final-layer weights to LDS ----
    if (tid < 48)          wsm[tid] = ihw1[tid];
    else if (tid < 51)     wsm[tid] = ihb1[tid - 48];
    else if (tid < 67)     wsm[tid] = ahw1[tid - 51];
    else if (tid == 67)    wsm[67]  = ahb1[0];
    else if (tid < 76)     wsm[tid] = chw1[tid - 68];
    else if (tid == 76)    wsm[76]  = chb1[0];

    // ---- initial state ----
    if (tid < 512) {
        int r = tid >> 5, c8 = (tid & 31) * 8;
#pragma unroll
        for (int j = 0; j < 8; ++j)
            zin[r * ZINS + 64 + c8 + j] = (_Float16)hx[(bg + r) * HN + c8 + j];
        int c2 = (tid & 31) * 2;
        const float* xp = &x[((size_t)(bg + r) * SN + 0) * INN + c2];
        zin[r * ZINS + c2]     = (_Float16)xp[0];
        zin[r * ZINS + c2 + 1] = (_Float16)xp[1];
    }
    if (tid < 16) tsb[0][tid] = tsp[(bg + tid) * SN + 0];

    // ---- per-lane column biases (each wave owns colgroup wv) ----
    const float b0v = b0[wv * 16 + lo];
    const float b1v = b1[wv * 16 + lo];

    // ---- register-resident W0/W1 fragments (1 colgroup per wave) ----
    h8 w0f[10], w1f[8];
#pragma unroll
    for (int kk = 0; kk < 10; ++kk) w0f[kk] = loadB<256>(w0, wv * 16 + lo, kk * 32 + hi8);
#pragma unroll
    for (int kk = 0; kk < 8; ++kk)  w1f[kk] = loadB<256>(w1, wv * 16 + lo, kk * 32 + hi8);

    // ---- head unit fragments -> LDS (waves 0-7; unit = wv) ----
    const int hm   = wv >> 1;
    const int hcol = sbase + (wv & 1) * 16 + lo;
    float hb = 0.0f;
    if (wv < 8) {
        const float* hwp = (hm == 0) ? f1w : (hm == 1) ? f2w : (hm == 2) ? taw : tbw;
        const float* hbp = (hm == 0) ? f1b : (hm == 1) ? f2b : (hm == 2) ? tab : tbb;
        hb = hbp[hcol];
#pragma unroll
        for (int kk = 0; kk < 8; ++kk) {
            h8 f = loadB<256>(hwp, hcol, kk * 32 + hi8);
            *(h8*)&hdl[((wv * 8 + kk) * 64 + lane) * 8] = f;
        }
    }
    // ---- proj fragments -> LDS (waves 8-11; unit = wv-8) ----
    float pbv = 0.0f;
    if (wv >= 8 && wv < 12) {
        int u = wv - 8;
        pbv = pbias[u * 16 + lo];
#pragma unroll
        for (int kk = 0; kk < 8; ++kk) {
            h8 f = loadB<64>(pw, u * 16 + lo, kk * 32 + hi8);
            *(h8*)&pfl[((kk * 4 + u) * 64 + lane) * 8] = f;
        }
    }
    // ---- head-hidden weights (waves 12-14) ----
    h8 hwf[2] = {};
    float hbv = 0.0f;
    if (wv == 12) {
        hbv = ihb0[lo];
#pragma unroll
        for (int kk = 0; kk < 2; ++kk) hwf[kk] = loadB<16>(ihw0, lo, kk * 32 + hi8);
    } else if (wv == 13) {
        hbv = ahb0[lo];
#pragma unroll
        for (int kk = 0; kk < 2; ++kk) hwf[kk] = loadB<16>(ahw0, lo, kk * 32 + hi8);
    } else if (wv == 14) {
        int cc = (lo < 8) ? lo : 0;
        hbv = (lo < 8) ? chb0[lo] : 0.0f;
#pragma unroll
        for (int kk = 0; kk < 2; ++kk) hwf[kk] = loadB<8>(chw0, cc, kk * 32 + hi8);
    }

    __syncthreads();

    for (int t = 0; t <= SN; ++t) {
        const int pr = t & 7;   // which block runs duty (outputs for t-1) this step

        // ===== P1: z0 = lecun([x|h] @ W0 + b0); wave wv -> colgroup wv =====
        if (t < SN) {
            fx4 acc = {b0v, b0v, b0v, b0v};
#pragma unroll
            for (int kk = 0; kk < 10; ++kk) {
                h8 a = *(const h8*)&zin[lo * ZINS + kk * 32 + hi8];
                acc = mfma16(a, w0f[kk], acc);
            }
#pragma unroll
            for (int i = 0; i < 4; ++i)
                z0b[(hi * 4 + i) * ZBS + wv * 16 + lo] = (_Float16)lecun_tanh(acc[i]);
        }
        __syncthreads();  // S1

        // x/ts prefetch for t+1 (zin x-region dead after z0)
        if (t + 1 < SN && tid < 512) {
            int r = tid >> 5, c2 = (tid & 31) * 2;
            const float* xp = &x[((size_t)(bg + r) * SN + (t + 1)) * INN + c2];
            zin[r * ZINS + c2]     = (_Float16)xp[0];
            zin[r * ZINS + c2 + 1] = (_Float16)xp[1];
            if (tid < 16) tsb[(t + 1) & 1][tid] = tsp[(bg + tid) * SN + t + 1];
        }

        // ===== P2: z1 = lecun(z0 @ W1 + b1) =====
        if (t < SN) {
            fx4 acc = {b1v, b1v, b1v, b1v};
#pragma unroll
            for (int kk = 0; kk < 8; ++kk) {
                h8 a = *(const h8*)&z0b[lo * ZBS + kk * 32 + hi8];
                acc = mfma16(a, w1f[kk], acc);
            }
#pragma unroll
            for (int i = 0; i < 4; ++i)
                z1b[(hi * 4 + i) * ZBS + wv * 16 + lo] = (_Float16)lecun_tanh(acc[i]);
        }
        __syncthreads();  // S2

        // ===== P3: heads on waves 0-7  ||  duty proj(t-1) on waves 8-11 =====
        if (t < SN && wv < 8) {
            fx4 acc = {hb, hb, hb, hb};
#pragma unroll
            for (int kk = 0; kk < 8; ++kk) {
                h8 a = *(const h8*)&z1b[lo * ZBS + kk * 32 + hi8];
                h8 b = *(const h8*)&hdl[((wv * 8 + kk) * 64 + lane) * 8];
                acc = mfma16(a, b, acc);
            }
#pragma unroll
            for (int i = 0; i < 4; ++i)
                htmp[(hm * 16 + hi * 4 + i) * HTS + (wv & 1) * 16 + lo] = acc[i];
        }
        if (t >= 1 && c == pr && wv >= 8 && wv < 12) {
            int u = wv - 8;
            fx4 acc = {pbv, pbv, pbv, pbv};
#pragma unroll
            for (int kk = 0; kk < 8; ++kk) {
                h8 a = *(const h8*)&zin[lo * ZINS + 64 + kk * 32 + hi8];
                h8 b = *(const h8*)&pfl[((kk * 4 + u) * 64 + lane) * 8];
                acc = mfma16(a, b, acc);
            }
#pragma unroll
            for (int i = 0; i < 4; ++i)
                cfcb[(hi * 4 + i) * CFS + u * 16 + lo] = (_Float16)acc[i];
        }
        __syncthreads();  // S3

        // ===== P4: combine+publish (tid<128)  ||  duty head-hiddens (waves 12-14) =====
        if (t < SN && tid < 128) {
            int r = tid >> 3, c4 = (tid & 7) * 4;
            h4u pk;
#pragma unroll
            for (int k = 0; k < 4; ++k) {
                float a1v = htmp[(0 * 16 + r) * HTS + c4 + k];
                float a2v = htmp[(1 * 16 + r) * HTS + c4 + k];
                float a3v = htmp[(2 * 16 + r) * HTS + c4 + k];
                float a4v = htmp[(3 * 16 + r) * HTS + c4 + k];
                float tv  = tsb[t & 1][r];
                float ff1 = fast_tanh(a1v);
                float ff2 = fast_tanh(a2v);
                float ti  = fast_sig(a3v * tv + a4v);
                float hn  = ff1 + ti * (ff2 - ff1);
                pk.h[k] = (_Float16)hn;
                if (t == SN - 1) out[OFF_HN + (bg + r) * HN + sbase + c4 + k] = hn;
            }
            size_t idx = (((size_t)((t + 1) & 1) * 256) + g * 16 + r) * 64 + (sbase + c4) / 4;
            __hip_atomic_store(&hbuf[idx], pk.u, __ATOMIC_RELAXED, __HIP_MEMORY_SCOPE_AGENT);
        }
        if (t >= 1 && c == pr && wv >= 12 && wv < 15) {
            fx4 acc = {hbv, hbv, hbv, hbv};
#pragma unroll
            for (int kk = 0; kk < 2; ++kk) {
                h8 a = *(const h8*)&cfcb[lo * CFS + kk * 32 + hi8];
                acc = mfma16(a, hwf[kk], acc);
            }
#pragma unroll
            for (int i = 0; i < 4; ++i) {
                float v = acc[i];
                v = v * fast_sig(v);
                int r = hi * 4 + i;
                if (wv == 12)      hidI[r * 16 + lo] = v;
                else if (wv == 13) hidA[r * 16 + lo] = v;
                else if (lo < 8)   hidC[r * 8 + lo]  = v;
            }
        }
        __syncthreads();  // S4 (drains publish stores before flag)
        if (t < SN && tid == 0)
            __hip_atomic_store(&flags[(g * 8 + c) * FLAG_STRIDE], (unsigned)(t + 1),
                               __ATOMIC_RELAXED, __HIP_MEMORY_SCOPE_AGENT);

        // ===== P5: duty final MLPs -> outputs(t-1) (waves 8-9)  ||  poll =====
        if (t >= 1 && c == pr && tid >= 512 && tid < 592) {
            int local = tid - 512;
            int r = local / 5, o = local % 5;
            int tc = t - 1;
            int b = bg + r;
            if (o < 3) {
                float s = wsm[48 + o];
#pragma unroll
                for (int u = 0; u < 16; ++u) s += hidI[r * 16 + u] * wsm[u * 3 + o];
                out[(size_t)(b * SN + tc) * 3 + o] = softplus_f(s);
            } else if (o == 3) {
                float s = wsm[67];
#pragma unroll
                for (int u = 0; u < 16; ++u) s += hidA[r * 16 + u] * wsm[51 + u];
                out[OFF_ACT + b * SN + tc] = fast_tanh(s);
            } else {
                float s = wsm[76];
#pragma unroll
                for (int u = 0; u < 8; ++u) s += hidC[r * 8 + u] * wsm[68 + u];
                out[OFF_CONF + b * SN + tc] = fast_sig(s);
            }
        }
        if (t < SN) {
            if (tid < 8) {
                unsigned target = (unsigned)(t + 1);
                while (__hip_atomic_load(&flags[(g * 8 + tid) * FLAG_STRIDE],
                                         __ATOMIC_RELAXED, __HIP_MEMORY_SCOPE_AGENT) < target) {}
            }
            __syncthreads();  // S5
            if (tid < 512) {
                int r = tid >> 5, c8 = (tid & 31) * 8;
                size_t idx = (((size_t)((t + 1) & 1) * 256) + g * 16 + r) * 64 + c8 / 4;
                u64 v0 = __hip_atomic_load(&hbuf[idx],     __ATOMIC_RELAXED, __HIP_MEMORY_SCOPE_AGENT);
                u64 v1 = __hip_atomic_load(&hbuf[idx + 1], __ATOMIC_RELAXED, __HIP_MEMORY_SCOPE_AGENT);
                *(u64*)&zin[r * ZINS + 64 + c8]     = v0;
                *(u64*)&zin[r * ZINS + 64 + c8 + 4] = v1;
            }
        }
        __syncthreads();  // S6
    }
}

extern "C" void kernel_launch(void* const* d_in, const int* in_sizes, int n_in,
                              void* d_out, int out_size, void* d_ws, size_t ws_size,
                              hipStream_t stream) {
    (void)in_sizes; (void)n_in; (void)out_size; (void)ws_size;
    const float* p[29];
    for (int i = 0; i < 29; ++i) p[i] = (const float*)d_in[i];
    unsigned int* flags = (unsigned int*)d_ws;
    u64* hbuf = (u64*)((char*)d_ws + FLAG_BYTES);
    hipMemsetAsync(d_ws, 0, FLAG_BYTES, stream);
    hipLaunchKernelGGL(lh_scan_kernel, dim3(128), dim3(1024), 0, stream,
        p[0], p[1], p[2], p[3], p[4], p[5], p[6], p[7], p[8], p[9], p[10], p[11], p[12],
        p[13], p[14], p[15], p[16], p[17], p[18], p[19], p[20], p[21], p[22], p[23],
        p[24], p[25], p[26], p[27], p[28], (float*)d_out, flags, hbuf);
}

// Round 9
// 2818.205 us; speedup vs baseline: 1.1089x; 1.1089x over previous
//
#include <hip/hip_runtime.h>
#include <hip/hip_bf16.h>

// Sizes (fixed by the reference)
#define BN  256
#define SN  512
#define INN 64
#define HN  256
#define MN  64

// LDS strides (f16 elems unless noted)
#define ZINS 328   // zin: [x(64) | h(256)] + 8 pad
#define ZBS  264   // z0/z1: 256 + 8
#define CFS  72    // cfc: 64 + 8
#define HTS  36    // htmp row stride (f32)

// Output offsets (f32 elements)
#define OFF_ACT  393216
#define OFF_CONF 524288
#define OFF_HN   655360

#define FLAG_STRIDE 32        // u32 per flag slot (128 B line spacing)
#define FLAG_BYTES  16384

typedef _Float16 h8 __attribute__((ext_vector_type(8)));
typedef float fx4 __attribute__((ext_vector_type(4)));
typedef unsigned long long u64;
union h4u { _Float16 h[4]; u64 u; };

__device__ __forceinline__ fx4 mfma16(h8 a, h8 b, fx4 c) {
    return __builtin_amdgcn_mfma_f32_16x16x32_f16(a, b, c, 0, 0, 0);
}
__device__ __forceinline__ float fast_tanh(float x) {
    float e = __expf(2.0f * x);
    return 1.0f - 2.0f / (e + 1.0f);
}
__device__ __forceinline__ float fast_sig(float x) { return 1.0f / (1.0f + __expf(-x)); }
__device__ __forceinline__ float lecun_tanh(float x) { return 1.7159f * fast_tanh(0.666f * x); }
__device__ __forceinline__ float softplus_f(float x) {
    return fmaxf(x, 0.0f) + __logf(1.0f + __expf(-fabsf(x)));
}

template <int NW>
__device__ __forceinline__ h8 loadB(const float* __restrict__ w, int col, int kbase) {
    h8 r;
#pragma unroll
    for (int j = 0; j < 8; ++j) r[j] = (_Float16)w[(kbase + j) * NW + col];
    return r;
}

__global__ void __launch_bounds__(256, 1) lh_scan_kernel(
    const float* __restrict__ x, const float* __restrict__ tsp, const float* __restrict__ hx,
    const float* __restrict__ w0, const float* __restrict__ b0,
    const float* __restrict__ w1, const float* __restrict__ b1,
    const float* __restrict__ f1w, const float* __restrict__ f1b,
    const float* __restrict__ f2w, const float* __restrict__ f2b,
    const float* __restrict__ taw, const float* __restrict__ tab,
    const float* __restrict__ tbw, const float* __restrict__ tbb,
    const float* __restrict__ pw, const float* __restrict__ pbias,
    const float* __restrict__ ihw0, const float* __restrict__ ihb0,
    const float* __restrict__ ihw1, const float* __restrict__ ihb1,
    const float* __restrict__ ahw0, const float* __restrict__ ahb0,
    const float* __restrict__ ahw1, const float* __restrict__ ahb1,
    const float* __restrict__ chw0, const float* __restrict__ chb0,
    const float* __restrict__ chw1, const float* __restrict__ chb1,
    float* __restrict__ out, unsigned int* __restrict__ flags,
    u64* __restrict__ hbuf)
{
    __shared__ __align__(16) _Float16 zin[16 * ZINS];        // [x(0..63) | h(64..319)]
    __shared__ __align__(16) _Float16 z0b[16 * ZBS];
    __shared__ __align__(16) _Float16 z1b[16 * ZBS];
    __shared__ __align__(16) _Float16 cfcb[16 * CFS];
    __shared__ __align__(16) _Float16 pfl[8 * 4 * 64 * 8];   // proj B-frags [kk][cg][lane][8]
    __shared__ __align__(16) float htmp[4 * 16 * HTS];
    __shared__ float hidI[16 * 16];
    __shared__ float hidA[16 * 16];
    __shared__ float hidC[16 * 8];
    __shared__ float tsb[2][16];
    __shared__ float wsm[80];

    const int tid  = threadIdx.x;
    const int wv   = tid >> 6;          // 0..3
    const int lane = tid & 63;
    const int lo   = lane & 15;
    const int hi   = lane >> 4;
    const int hi8  = hi * 8;

    const int bid   = blockIdx.x;
    const int xcd   = bid & 7;
    const int c     = (bid >> 3) & 7;   // column-slice id 0..7
    const int gsel  = bid >> 6;
    const int g     = xcd + 8 * gsel;   // batch group; 8 blocks share g (same-XCD heuristic)
    const int bg    = g * 16;
    const int sbase = c * 32;           // this block's 32 head columns

    // ---- small final-layer weights to LDS ----
    if (tid < 48)          wsm[tid] = ihw1[tid];
    else if (tid < 51)     wsm[tid] = ihb1[tid - 48];
    else if (tid < 67)     wsm[tid] = ahw1[tid - 51];
    else if (tid == 67)    wsm[67]  = ahb1[0];
    else if (tid < 76)     wsm[tid] = chw1[tid - 68];
    else if (tid == 76)    wsm[76]  = chb1[0];

    // ---- initial state: hx and x(0) into zin ----
    {
        int r = tid >> 4, c16 = (tid & 15) * 16;
#pragma unroll
        for (int j = 0; j < 16; ++j)
            zin[r * ZINS + 64 + c16 + j] = (_Float16)hx[(bg + r) * HN + c16 + j];
        int c4 = (tid & 15) * 4;
        fx4 xv = *(const fx4*)&x[((size_t)(bg + r) * SN + 0) * INN + c4];
        h4u pk;
#pragma unroll
        for (int j = 0; j < 4; ++j) pk.h[j] = (_Float16)xv[j];
        *(u64*)&zin[r * ZINS + c4] = pk.u;
    }
    if (tid < 16) tsb[0][tid] = tsp[(bg + tid) * SN + 0];

    // ---- per-wave column ownership: colgroups wv*4..wv*4+3 ----
    float b0v[4], b1v[4];
#pragma unroll
    for (int q = 0; q < 4; ++q) {
        b0v[q] = b0[(wv * 4 + q) * 16 + lo];
        b1v[q] = b1[(wv * 4 + q) * 16 + lo];
    }

    // head: wave wv owns matrix wv (f1,f2,ta,tb), both 16-col halves of the block slice
    const float* hwp = (wv == 0) ? f1w : (wv == 1) ? f2w : (wv == 2) ? taw : tbw;
    const float* hbp = (wv == 0) ? f1b : (wv == 1) ? f2b : (wv == 2) ? tab : tbb;
    float hbs[2] = { hbp[sbase + lo], hbp[sbase + 16 + lo] };

    // ---- register-resident weights ----
    h8 w0f[4][10], w1f[4][8], hdf[2][8];
#pragma unroll
    for (int q = 0; q < 4; ++q) {
#pragma unroll
        for (int kk = 0; kk < 10; ++kk)
            w0f[q][kk] = loadB<256>(w0, (wv * 4 + q) * 16 + lo, kk * 32 + hi8);
#pragma unroll
        for (int kk = 0; kk < 8; ++kk)
            w1f[q][kk] = loadB<256>(w1, (wv * 4 + q) * 16 + lo, kk * 32 + hi8);
    }
#pragma unroll
    for (int s = 0; s < 2; ++s)
#pragma unroll
        for (int kk = 0; kk < 8; ++kk)
            hdf[s][kk] = loadB<256>(hwp, sbase + s * 16 + lo, kk * 32 + hi8);

    // proj B-frags -> LDS (wave wv loads colgroup wv)
    {
#pragma unroll
        for (int kk = 0; kk < 8; ++kk) {
            h8 f = loadB<64>(pw, wv * 16 + lo, kk * 32 + hi8);
            *(h8*)&pfl[((kk * 4 + wv) * 64 + lane) * 8] = f;
        }
    }
    float pbv[2] = { 0.0f, 0.0f };
    if (wv >= 2) {
        pbv[0] = pbias[((wv - 2) * 2 + 0) * 16 + lo];
        pbv[1] = pbias[((wv - 2) * 2 + 1) * 16 + lo];
    }
    // head-hidden weights: wv0->I, wv1->A, wv2->C
    h8 hwf[2] = {};
    float hbv = 0.0f;
    if (wv == 0) {
        hbv = ihb0[lo];
#pragma unroll
        for (int kk = 0; kk < 2; ++kk) hwf[kk] = loadB<16>(ihw0, lo, kk * 32 + hi8);
    } else if (wv == 1) {
        hbv = ahb0[lo];
#pragma unroll
        for (int kk = 0; kk < 2; ++kk) hwf[kk] = loadB<16>(ahw0, lo, kk * 32 + hi8);
    } else if (wv == 2) {
        int cc = (lo < 8) ? lo : 0;
        hbv = (lo < 8) ? chb0[lo] : 0.0f;
#pragma unroll
        for (int kk = 0; kk < 2; ++kk) hwf[kk] = loadB<8>(chw0, cc, kk * 32 + hi8);
    }

    __syncthreads();

    for (int t = 0; t <= SN; ++t) {
        const int pr = t & 7;

        // ===== P1: z0 = lecun([x|h] @ W0 + b0); 4 colgroups/wave, A reused 4x =====
        if (t < SN) {
            fx4 a0 = {b0v[0], b0v[0], b0v[0], b0v[0]};
            fx4 a1 = {b0v[1], b0v[1], b0v[1], b0v[1]};
            fx4 a2 = {b0v[2], b0v[2], b0v[2], b0v[2]};
            fx4 a3 = {b0v[3], b0v[3], b0v[3], b0v[3]};
#pragma unroll
            for (int kk = 0; kk < 10; ++kk) {
                h8 a = *(const h8*)&zin[lo * ZINS + kk * 32 + hi8];
                a0 = mfma16(a, w0f[0][kk], a0);
                a1 = mfma16(a, w0f[1][kk], a1);
                a2 = mfma16(a, w0f[2][kk], a2);
                a3 = mfma16(a, w0f[3][kk], a3);
            }
#pragma unroll
            for (int i = 0; i < 4; ++i) {
                int r = hi * 4 + i;
                z0b[r * ZBS + (wv * 4 + 0) * 16 + lo] = (_Float16)lecun_tanh(a0[i]);
                z0b[r * ZBS + (wv * 4 + 1) * 16 + lo] = (_Float16)lecun_tanh(a1[i]);
                z0b[r * ZBS + (wv * 4 + 2) * 16 + lo] = (_Float16)lecun_tanh(a2[i]);
                z0b[r * ZBS + (wv * 4 + 3) * 16 + lo] = (_Float16)lecun_tanh(a3[i]);
            }
        }
        __syncthreads();  // S1

        // ===== P2: z1 = lecun(z0 @ W1 + b1)  ||  x/ts prefetch(t+1) =====
        if (t + 1 < SN) {
            int r = tid >> 4, c4 = (tid & 15) * 4;
            fx4 xv = *(const fx4*)&x[((size_t)(bg + r) * SN + (t + 1)) * INN + c4];
            h4u pk;
#pragma unroll
            for (int j = 0; j < 4; ++j) pk.h[j] = (_Float16)xv[j];
            *(u64*)&zin[r * ZINS + c4] = pk.u;
            if (tid < 16) tsb[(t + 1) & 1][tid] = tsp[(bg + tid) * SN + t + 1];
        }
        if (t < SN) {
            fx4 a0 = {b1v[0], b1v[0], b1v[0], b1v[0]};
            fx4 a1 = {b1v[1], b1v[1], b1v[1], b1v[1]};
            fx4 a2 = {b1v[2], b1v[2], b1v[2], b1v[2]};
            fx4 a3 = {b1v[3], b1v[3], b1v[3], b1v[3]};
#pragma unroll
            for (int kk = 0; kk < 8; ++kk) {
                h8 a = *(const h8*)&z0b[lo * ZBS + kk * 32 + hi8];
                a0 = mfma16(a, w1f[0][kk], a0);
                a1 = mfma16(a, w1f[1][kk], a1);
                a2 = mfma16(a, w1f[2][kk], a2);
                a3 = mfma16(a, w1f[3][kk], a3);
            }
#pragma unroll
            for (int i = 0; i < 4; ++i) {
                int r = hi * 4 + i;
                z1b[r * ZBS + (wv * 4 + 0) * 16 + lo] = (_Float16)lecun_tanh(a0[i]);
                z1b[r * ZBS + (wv * 4 + 1) * 16 + lo] = (_Float16)lecun_tanh(a1[i]);
                z1b[r * ZBS + (wv * 4 + 2) * 16 + lo] = (_Float16)lecun_tanh(a2[i]);
                z1b[r * ZBS + (wv * 4 + 3) * 16 + lo] = (_Float16)lecun_tanh(a3[i]);
            }
        }
        __syncthreads();  // S2

        // ===== P3: head matrix wv, 2 colgroups of this block's 32-col slice =====
        if (t < SN) {
            fx4 a0 = {hbs[0], hbs[0], hbs[0], hbs[0]};
            fx4 a1 = {hbs[1], hbs[1], hbs[1], hbs[1]};
#pragma unroll
            for (int kk = 0; kk < 8; ++kk) {
                h8 a = *(const h8*)&z1b[lo * ZBS + kk * 32 + hi8];
                a0 = mfma16(a, hdf[0][kk], a0);
                a1 = mfma16(a, hdf[1][kk], a1);
            }
#pragma unroll
            for (int i = 0; i < 4; ++i) {
                htmp[(wv * 16 + hi * 4 + i) * HTS + lo]      = a0[i];
                htmp[(wv * 16 + hi * 4 + i) * HTS + 16 + lo] = a1[i];
            }
        }
        __syncthreads();  // S3

        // ===== P4: combine+publish (waves 0-1)  ||  duty proj (waves 2-3) =====
        if (t < SN && tid < 128) {
            int r = tid >> 3, c4 = (tid & 7) * 4;
            fx4 v0 = *(const fx4*)&htmp[(0 * 16 + r) * HTS + c4];
            fx4 v1 = *(const fx4*)&htmp[(1 * 16 + r) * HTS + c4];
            fx4 v2 = *(const fx4*)&htmp[(2 * 16 + r) * HTS + c4];
            fx4 v3 = *(const fx4*)&htmp[(3 * 16 + r) * HTS + c4];
            float tv = tsb[t & 1][r];
            h4u pk;
#pragma unroll
            for (int k = 0; k < 4; ++k) {
                float ff1 = fast_tanh(v0[k]);
                float ff2 = fast_tanh(v1[k]);
                float ti  = fast_sig(v2[k] * tv + v3[k]);
                float hn  = ff1 + ti * (ff2 - ff1);
                pk.h[k] = (_Float16)hn;
                if (t == SN - 1) out[OFF_HN + (bg + r) * HN + sbase + c4 + k] = hn;
            }
            size_t idx = (((size_t)((t + 1) & 1) * 256) + g * 16 + r) * 64 + (sbase + c4) / 4;
            __hip_atomic_store(&hbuf[idx], pk.u, __ATOMIC_RELAXED, __HIP_MEMORY_SCOPE_AGENT);
        }
        if (t >= 1 && c == pr && wv >= 2) {
            fx4 a0 = {pbv[0], pbv[0], pbv[0], pbv[0]};
            fx4 a1 = {pbv[1], pbv[1], pbv[1], pbv[1]};
            int cg0 = (wv - 2) * 2, cg1 = cg0 + 1;
#pragma unroll
            for (int kk = 0; kk < 8; ++kk) {
                h8 a = *(const h8*)&zin[lo * ZINS + 64 + kk * 32 + hi8];
                h8 f0 = *(const h8*)&pfl[((kk * 4 + cg0) * 64 + lane) * 8];
                h8 f1 = *(const h8*)&pfl[((kk * 4 + cg1) * 64 + lane) * 8];
                a0 = mfma16(a, f0, a0);
                a1 = mfma16(a, f1, a1);
            }
#pragma unroll
            for (int i = 0; i < 4; ++i) {
                cfcb[(hi * 4 + i) * CFS + cg0 * 16 + lo] = (_Float16)a0[i];
                cfcb[(hi * 4 + i) * CFS + cg1 * 16 + lo] = (_Float16)a1[i];
            }
        }
        __syncthreads();  // S4
        if (t < SN && tid == 0)
            __hip_atomic_store(&flags[(g * 8 + c) * FLAG_STRIDE], (unsigned)(t + 2),
                               __ATOMIC_RELAXED, __HIP_MEMORY_SCOPE_AGENT);

        // ===== P5: duty head-hiddens (waves 0-2)  ||  poll (wave 3) =====
        if (t >= 1 && c == pr && wv < 3) {
            fx4 acc = {hbv, hbv, hbv, hbv};
#pragma unroll
            for (int kk = 0; kk < 2; ++kk) {
                h8 a = *(const h8*)&cfcb[lo * CFS + kk * 32 + hi8];
                acc = mfma16(a, hwf[kk], acc);
            }
#pragma unroll
            for (int i = 0; i < 4; ++i) {
                float v = acc[i];
                v = v * fast_sig(v);
                int r = hi * 4 + i;
                if (wv == 0)       hidI[r * 16 + lo] = v;
                else if (wv == 1)  hidA[r * 16 + lo] = v;
                else if (lo < 8)   hidC[r * 8 + lo]  = v;
            }
        }
        if (t < SN && wv == 3 && lane < 8) {
            unsigned target = (unsigned)(t + 2);
            while (__hip_atomic_load(&flags[(g * 8 + lane) * FLAG_STRIDE],
                                     __ATOMIC_RELAXED, __HIP_MEMORY_SCOPE_AGENT) < target) {}
        }
        __syncthreads();  // S5

        // ===== P6: stage h(t+1) -> zin.h  ||  duty outputs(t-1) =====
        if (t < SN) {
            int r = tid >> 4, cw = (tid & 15) * 16;
            size_t idx = (((size_t)((t + 1) & 1) * 256) + g * 16 + r) * 64 + cw / 4;
            u64 v0 = __hip_atomic_load(&hbuf[idx],     __ATOMIC_RELAXED, __HIP_MEMORY_SCOPE_AGENT);
            u64 v1 = __hip_atomic_load(&hbuf[idx + 1], __ATOMIC_RELAXED, __HIP_MEMORY_SCOPE_AGENT);
            u64 v2 = __hip_atomic_load(&hbuf[idx + 2], __ATOMIC_RELAXED, __HIP_MEMORY_SCOPE_AGENT);
            u64 v3 = __hip_atomic_load(&hbuf[idx + 3], __ATOMIC_RELAXED, __HIP_MEMORY_SCOPE_AGENT);
            if (t >= 1 && c == pr && tid < 80) {
                int rr = tid / 5, o = tid % 5;
                int tc = t - 1;
                int b = bg + rr;
                if (o < 3) {
                    float s = wsm[48 + o];
#pragma unroll
                    for (int u = 0; u < 16; ++u) s += hidI[rr * 16 + u] * wsm[u * 3 + o];
                    out[(size_t)(b * SN + tc) * 3 + o] = softplus_f(s);
                } else if (o == 3) {
                    float s = wsm[67];
#pragma unroll
                    for (int u = 0; u < 16; ++u) s += hidA[rr * 16 + u] * wsm[51 + u];
                    out[OFF_ACT + b * SN + tc] = fast_tanh(s);
                } else {
                    float s = wsm[76];
#pragma unroll
                    for (int u = 0; u < 8; ++u) s += hidC[rr * 8 + u] * wsm[68 + u];
                    out[OFF_CONF + b * SN + tc] = fast_sig(s);
                }
            }
            *(u64*)&zin[r * ZINS + 64 + cw]      = v0;
            *(u64*)&zin[r * ZINS + 64 + cw + 4]  = v1;
            *(u64*)&zin[r * ZINS + 64 + cw + 8]  = v2;
            *(u64*)&zin[r * ZINS + 64 + cw + 12] = v3;
        } else if (t >= 1 && c == pr && tid < 80) {
            int rr = tid / 5, o = tid % 5;
            int tc = t - 1;
            int b = bg + rr;
            if (o < 3) {
                float s = wsm[48 + o];
#pragma unroll
                for (int u = 0; u < 16; ++u) s += hidI[rr * 16 + u] * wsm[u * 3 + o];
                out[(size_t)(b * SN + tc) * 3 + o] = softplus_f(s);
            } else if (o == 3) {
                float s = wsm[67];
#pragma unroll
                for (int u = 0; u < 16; ++u) s += hidA[rr * 16 + u] * wsm[51 + u];
                out[OFF_ACT + b * SN + tc] = fast_tanh(s);
            } else {
                float s = wsm[76];
#pragma unroll
                for (int u = 0; u < 8; ++u) s += hidC[rr * 8 + u] * wsm[68 + u];
                out[OFF_CONF + b * SN + tc] = fast_sig(s);
            }
        }
        __syncthreads();  // S6
    }
}

extern "C" void kernel_launch(void* const* d_in, const int* in_sizes, int n_in,
                              void* d_out, int out_size, void* d_ws, size_t ws_size,
                              hipStream_t stream) {
    (void)in_sizes; (void)n_in; (void)out_size; (void)ws_size;
    const float* p[29];
    for (int i = 0; i < 29; ++i) p[i] = (const float*)d_in[i];
    unsigned int* flags = (unsigned int*)d_ws;
    u64* hbuf = (u64*)((char*)d_ws + FLAG_BYTES);
    hipMemsetAsync(d_ws, 0, FLAG_BYTES, stream);
    hipLaunchKernelGGL(lh_scan_kernel, dim3(128), dim3(256), 0, stream,
        p[0], p[1], p[2], p[3], p[4], p[5], p[6], p[7], p[8], p[9], p[10], p[11], p[12],
        p[13], p[14], p[15], p[16], p[17], p[18], p[19], p[20], p[21], p[22], p[23],
        p[24], p[25], p[26], p[27], p[28], (float*)d_out, flags, hbuf);
}

// Round 10
// 2453.412 us; speedup vs baseline: 1.2738x; 1.1487x over previous
//
#include <hip/hip_runtime.h>
#include <hip/hip_bf16.h>

// Sizes (fixed by the reference)
#define BN  256
#define SN  512
#define INN 64
#define HN  256
#define MN  64

// LDS strides (f16 elems unless noted)
#define ZINS 328   // zin: [x(64) | h(256)] + 8 pad
#define ZBS  264   // z0/z1: 256 + 8
#define CFS  72    // cfc: 64 + 8
#define HTS  36    // htmp row stride (f32, 144 B -> fx4-aligned rows)

// Output offsets (f32 elements)
#define OFF_ACT  393216
#define OFF_CONF 524288
#define OFF_HN   655360

#define FLAG_STRIDE 32        // u32 per flag slot (128 B line spacing)
#define FLAG_BYTES  16384

typedef _Float16 h8 __attribute__((ext_vector_type(8)));
typedef float fx4 __attribute__((ext_vector_type(4)));
typedef unsigned long long u64;
union h4u { _Float16 h[4]; u64 u; };

__device__ __forceinline__ fx4 mfma16(h8 a, h8 b, fx4 c) {
    return __builtin_amdgcn_mfma_f32_16x16x32_f16(a, b, c, 0, 0, 0);
}
__device__ __forceinline__ float fast_tanh(float x) {
    float e = __expf(2.0f * x);
    return 1.0f - 2.0f / (e + 1.0f);
}
__device__ __forceinline__ float fast_sig(float x) { return 1.0f / (1.0f + __expf(-x)); }
__device__ __forceinline__ float lecun_tanh(float x) { return 1.7159f * fast_tanh(0.666f * x); }
__device__ __forceinline__ float softplus_f(float x) {
    return fmaxf(x, 0.0f) + __logf(1.0f + __expf(-fabsf(x)));
}

template <int NW>
__device__ __forceinline__ h8 loadB(const float* __restrict__ w, int col, int kbase) {
    h8 r;
#pragma unroll
    for (int j = 0; j < 8; ++j) r[j] = (_Float16)w[(kbase + j) * NW + col];
    return r;
}

__global__ void __launch_bounds__(512, 1) lh_scan_kernel(
    const float* __restrict__ x, const float* __restrict__ tsp, const float* __restrict__ hx,
    const float* __restrict__ w0, const float* __restrict__ b0,
    const float* __restrict__ w1, const float* __restrict__ b1,
    const float* __restrict__ f1w, const float* __restrict__ f1b,
    const float* __restrict__ f2w, const float* __restrict__ f2b,
    const float* __restrict__ taw, const float* __restrict__ tab,
    const float* __restrict__ tbw, const float* __restrict__ tbb,
    const float* __restrict__ pw, const float* __restrict__ pbias,
    const float* __restrict__ ihw0, const float* __restrict__ ihb0,
    const float* __restrict__ ihw1, const float* __restrict__ ihb1,
    const float* __restrict__ ahw0, const float* __restrict__ ahb0,
    const float* __restrict__ ahw1, const float* __restrict__ ahb1,
    const float* __restrict__ chw0, const float* __restrict__ chb0,
    const float* __restrict__ chw1, const float* __restrict__ chb1,
    float* __restrict__ out, unsigned int* __restrict__ flags,
    u64* __restrict__ hbuf)
{
    __shared__ __align__(16) _Float16 zin[16 * ZINS];
    __shared__ __align__(16) _Float16 z0b[16 * ZBS];
    __shared__ __align__(16) _Float16 z1b[16 * ZBS];
    __shared__ __align__(16) _Float16 cfcb[16 * CFS];
    __shared__ __align__(16) _Float16 pfl[8 * 4 * 64 * 8];   // proj B-frags [kk][cg][lane][8]
    __shared__ __align__(16) _Float16 w1l[8 * 8 * 64 * 8];   // W1 cg1 B-frags [kk][wv][lane][8]
    __shared__ __align__(16) float htmp[4 * 16 * HTS];
    __shared__ float hidI[16 * 16];
    __shared__ float hidA[16 * 16];
    __shared__ float hidC[16 * 8];
    __shared__ float tsb[2][16];
    __shared__ float wsm[80];

    const int tid  = threadIdx.x;
    const int wv   = tid >> 6;
    const int lane = tid & 63;
    const int lo   = lane & 15;
    const int hi   = lane >> 4;
    const int hi8  = hi * 8;

    const int bid   = blockIdx.x;
    const int xcd   = bid & 7;
    const int c     = (bid >> 3) & 7;   // column-slice id 0..7
    const int gsel  = bid >> 6;
    const int g     = xcd + 8 * gsel;   // batch group; 8 blocks share g
    const int bg    = g * 16;
    const int sbase = c * 32;           // this block's 32 head columns

    // ---- small final-layer weights to LDS ----
    if (tid < 48)          wsm[tid] = ihw1[tid];
    else if (tid < 51)     wsm[tid] = ihb1[tid - 48];
    else if (tid < 67)     wsm[tid] = ahw1[tid - 51];
    else if (tid == 67)    wsm[67]  = ahb1[0];
    else if (tid < 76)     wsm[tid] = chw1[tid - 68];
    else if (tid == 76)    wsm[76]  = chb1[0];

    // ---- initial state ----
    {
        int r = tid >> 5, c8 = (tid & 31) * 8;
#pragma unroll
        for (int j = 0; j < 8; ++j)
            zin[r * ZINS + 64 + c8 + j] = (_Float16)hx[(bg + r) * HN + c8 + j];
        int c2 = (tid & 31) * 2;
        const float* xp = &x[((size_t)(bg + r) * SN + 0) * INN + c2];
        zin[r * ZINS + c2]     = (_Float16)xp[0];
        zin[r * ZINS + c2 + 1] = (_Float16)xp[1];
    }
    if (tid < 16) tsb[0][tid] = tsp[(bg + tid) * SN + 0];

    // ---- per-lane column biases ----
    const int cg0 = wv, cg1 = wv + 8;
    const float b00 = b0[cg0 * 16 + lo], b01 = b0[cg1 * 16 + lo];
    const float b10 = b1[cg0 * 16 + lo], b11 = b1[cg1 * 16 + lo];

    const int hm   = wv >> 1;
    const int hcol = sbase + (wv & 1) * 16 + lo;
    const float* hwp = (hm == 0) ? f1w : (hm == 1) ? f2w : (hm == 2) ? taw : tbw;
    const float* hbp = (hm == 0) ? f1b : (hm == 1) ? f2b : (hm == 2) ? tab : tbb;
    const float hb = hbp[hcol];

    // ---- register-resident weight fragments ----
    h8 w0f0[10], w0f1[10], w1f0[8], hdf[8];
#pragma unroll
    for (int kk = 0; kk < 10; ++kk) {
        w0f0[kk] = loadB<256>(w0, cg0 * 16 + lo, kk * 32 + hi8);
        w0f1[kk] = loadB<256>(w0, cg1 * 16 + lo, kk * 32 + hi8);
    }
#pragma unroll
    for (int kk = 0; kk < 8; ++kk) {
        w1f0[kk] = loadB<256>(w1, cg0 * 16 + lo, kk * 32 + hi8);
        hdf[kk]  = loadB<256>(hwp, hcol, kk * 32 + hi8);
        h8 f = loadB<256>(w1, cg1 * 16 + lo, kk * 32 + hi8);
        *(h8*)&w1l[((kk * 8 + wv) * 64 + lane) * 8] = f;
    }
    // proj fragments -> LDS (waves 0-3 load; duty waves 2-5 consume cg 0-3)
    if (wv < 4) {
#pragma unroll
        for (int kk = 0; kk < 8; ++kk) {
            h8 f = loadB<64>(pw, wv * 16 + lo, kk * 32 + hi8);
            *(h8*)&pfl[((kk * 4 + wv) * 64 + lane) * 8] = f;
        }
    }
    float pbv = 0.0f;
    if (wv >= 2 && wv < 6) pbv = pbias[(wv - 2) * 16 + lo];
    // head-hidden weights on duty waves 2(I), 3(A), 4(C)
    h8 hwf[2] = {};
    float hbv = 0.0f;
    if (wv == 2) {
        hbv = ihb0[lo];
#pragma unroll
        for (int kk = 0; kk < 2; ++kk) hwf[kk] = loadB<16>(ihw0, lo, kk * 32 + hi8);
    } else if (wv == 3) {
        hbv = ahb0[lo];
#pragma unroll
        for (int kk = 0; kk < 2; ++kk) hwf[kk] = loadB<16>(ahw0, lo, kk * 32 + hi8);
    } else if (wv == 4) {
        int cc = (lo < 8) ? lo : 0;
        hbv = (lo < 8) ? chb0[lo] : 0.0f;
#pragma unroll
        for (int kk = 0; kk < 2; ++kk) hwf[kk] = loadB<8>(chw0, cc, kk * 32 + hi8);
    }

    __syncthreads();

    // ---- prologue: z0 x-part for t=0 ----
    fx4 zx0 = {b00, b00, b00, b00}, zx1 = {b01, b01, b01, b01};
    {
        h8 ax0 = *(const h8*)&zin[lo * ZINS + 0 * 32 + hi8];
        h8 ax1 = *(const h8*)&zin[lo * ZINS + 1 * 32 + hi8];
        zx0 = mfma16(ax0, w0f0[0], zx0); zx1 = mfma16(ax0, w0f1[0], zx1);
        zx0 = mfma16(ax1, w0f0[1], zx0); zx1 = mfma16(ax1, w0f1[1], zx1);
    }

    for (int t = 0; t <= SN; ++t) {
        const int pr = t & 7;

        // ===== A: z0 h-part (x-part pre-accumulated in zx) =====
        if (t < SN) {
            fx4 a0 = zx0, a1 = zx1;
#pragma unroll
            for (int j = 0; j < 8; ++j) {
                h8 a = *(const h8*)&zin[lo * ZINS + 64 + j * 32 + hi8];
                a0 = mfma16(a, w0f0[j + 2], a0);
                a1 = mfma16(a, w0f1[j + 2], a1);
            }
#pragma unroll
            for (int i = 0; i < 4; ++i) {
                int r = hi * 4 + i;
                z0b[r * ZBS + cg0 * 16 + lo] = (_Float16)lecun_tanh(a0[i]);
                z0b[r * ZBS + cg1 * 16 + lo] = (_Float16)lecun_tanh(a1[i]);
            }
        }
        __syncthreads();  // S1

        // ===== B: x/ts prefetch(t+1) + z1 =====
        if (t + 1 < SN) {
            int r = tid >> 5, c2 = (tid & 31) * 2;
            const float* xp = &x[((size_t)(bg + r) * SN + (t + 1)) * INN + c2];
            zin[r * ZINS + c2]     = (_Float16)xp[0];
            zin[r * ZINS + c2 + 1] = (_Float16)xp[1];
            if (tid < 16) tsb[(t + 1) & 1][tid] = tsp[(bg + tid) * SN + t + 1];
        }
        if (t < SN) {
            fx4 a0 = {b10, b10, b10, b10}, a1 = {b11, b11, b11, b11};
#pragma unroll
            for (int kk = 0; kk < 8; ++kk) {
                h8 a = *(const h8*)&z0b[lo * ZBS + kk * 32 + hi8];
                h8 bf = *(const h8*)&w1l[((kk * 8 + wv) * 64 + lane) * 8];
                a0 = mfma16(a, w1f0[kk], a0);
                a1 = mfma16(a, bf, a1);
            }
#pragma unroll
            for (int i = 0; i < 4; ++i) {
                int r = hi * 4 + i;
                z1b[r * ZBS + cg0 * 16 + lo] = (_Float16)lecun_tanh(a0[i]);
                z1b[r * ZBS + cg1 * 16 + lo] = (_Float16)lecun_tanh(a1[i]);
            }
        }
        __syncthreads();  // S2

        // ===== C: heads (all 8 waves, one (matrix, colhalf) unit each) =====
        if (t < SN) {
            fx4 acc = {hb, hb, hb, hb};
#pragma unroll
            for (int kk = 0; kk < 8; ++kk) {
                h8 a = *(const h8*)&z1b[lo * ZBS + kk * 32 + hi8];
                acc = mfma16(a, hdf[kk], acc);
            }
#pragma unroll
            for (int i = 0; i < 4; ++i)
                htmp[(hm * 16 + hi * 4 + i) * HTS + (wv & 1) * 16 + lo] = acc[i];
        }
        __syncthreads();  // S3

        // ===== D: combine+publish (waves 0-1)  ||  duty proj (waves 2-5) =====
        if (t < SN && tid < 128) {
            int r = tid >> 3, c4 = (tid & 7) * 4;
            fx4 v0 = *(const fx4*)&htmp[(0 * 16 + r) * HTS + c4];
            fx4 v1 = *(const fx4*)&htmp[(1 * 16 + r) * HTS + c4];
            fx4 v2 = *(const fx4*)&htmp[(2 * 16 + r) * HTS + c4];
            fx4 v3 = *(const fx4*)&htmp[(3 * 16 + r) * HTS + c4];
            float tv = tsb[t & 1][r];
            h4u pk;
#pragma unroll
            for (int k = 0; k < 4; ++k) {
                float ff1 = fast_tanh(v0[k]);
                float ff2 = fast_tanh(v1[k]);
                float ti  = fast_sig(v2[k] * tv + v3[k]);
                float hn  = ff1 + ti * (ff2 - ff1);
                pk.h[k] = (_Float16)hn;
                if (t == SN - 1) out[OFF_HN + (bg + r) * HN + sbase + c4 + k] = hn;
            }
            size_t idx = (((size_t)((t + 1) & 1) * 256) + g * 16 + r) * 64 + (sbase + c4) / 4;
            __hip_atomic_store(&hbuf[idx], pk.u, __ATOMIC_RELAXED, __HIP_MEMORY_SCOPE_AGENT);
        }
        if (t >= 1 && c == pr && wv >= 2 && wv < 6) {
            int u = wv - 2;
            fx4 acc = {pbv, pbv, pbv, pbv};
#pragma unroll
            for (int kk = 0; kk < 8; ++kk) {
                h8 a = *(const h8*)&zin[lo * ZINS + 64 + kk * 32 + hi8];
                h8 b = *(const h8*)&pfl[((kk * 4 + u) * 64 + lane) * 8];
                acc = mfma16(a, b, acc);
            }
#pragma unroll
            for (int i = 0; i < 4; ++i)
                cfcb[(hi * 4 + i) * CFS + u * 16 + lo] = (_Float16)acc[i];
        }
        __syncthreads();  // S4 (drains publish stores + cfcb)
        if (t < SN && tid == 0)
            __hip_atomic_store(&flags[(g * 8 + c) * FLAG_STRIDE], (unsigned)(t + 1),
                               __ATOMIC_RELAXED, __HIP_MEMORY_SCOPE_AGENT);

        // ===== E: duty head-hiddens (waves 2-4)  ||  poll (wave 7) =====
        if (t >= 1 && c == pr && wv >= 2 && wv < 5) {
            fx4 acc = {hbv, hbv, hbv, hbv};
#pragma unroll
            for (int kk = 0; kk < 2; ++kk) {
                h8 a = *(const h8*)&cfcb[lo * CFS + kk * 32 + hi8];
                acc = mfma16(a, hwf[kk], acc);
            }
#pragma unroll
            for (int i = 0; i < 4; ++i) {
                float v = acc[i];
                v = v * fast_sig(v);
                int r = hi * 4 + i;
                if (wv == 2)       hidI[r * 16 + lo] = v;
                else if (wv == 3)  hidA[r * 16 + lo] = v;
                else if (lo < 8)   hidC[r * 8 + lo]  = v;
            }
        }
        if (t < SN && wv == 7 && lane < 8) {
            unsigned target = (unsigned)(t + 1);
            while (__hip_atomic_load(&flags[(g * 8 + lane) * FLAG_STRIDE],
                                     __ATOMIC_RELAXED, __HIP_MEMORY_SCOPE_AGENT) < target) {}
        }
        __syncthreads();  // S5

        // ===== F: h-load + z0x(t+1) + duty outputs(t-1) =====
        u64 v0 = 0, v1 = 0;
        int lr = tid >> 5, lc8 = (tid & 31) * 8;
        if (t < SN) {
            size_t idx = (((size_t)((t + 1) & 1) * 256) + g * 16 + lr) * 64 + lc8 / 4;
            v0 = __hip_atomic_load(&hbuf[idx],     __ATOMIC_RELAXED, __HIP_MEMORY_SCOPE_AGENT);
            v1 = __hip_atomic_load(&hbuf[idx + 1], __ATOMIC_RELAXED, __HIP_MEMORY_SCOPE_AGENT);
        }
        zx0 = fx4{b00, b00, b00, b00};
        zx1 = fx4{b01, b01, b01, b01};
        if (t + 1 < SN) {
            h8 ax0 = *(const h8*)&zin[lo * ZINS + 0 * 32 + hi8];
            h8 ax1 = *(const h8*)&zin[lo * ZINS + 1 * 32 + hi8];
            zx0 = mfma16(ax0, w0f0[0], zx0); zx1 = mfma16(ax0, w0f1[0], zx1);
            zx0 = mfma16(ax1, w0f0[1], zx0); zx1 = mfma16(ax1, w0f1[1], zx1);
        }
        if (t >= 1 && c == pr && tid >= 384 && tid < 464) {
            int local = tid - 384;
            int rr = local / 5, o = local % 5;
            int tc = t - 1;
            int b = bg + rr;
            if (o < 3) {
                float s = wsm[48 + o];
#pragma unroll
                for (int u = 0; u < 16; ++u) s += hidI[rr * 16 + u] * wsm[u * 3 + o];
                out[(size_t)(b * SN + tc) * 3 + o] = softplus_f(s);
            } else if (o == 3) {
                float s = wsm[67];
#pragma unroll
                for (int u = 0; u < 16; ++u) s += hidA[rr * 16 + u] * wsm[51 + u];
                out[OFF_ACT + b * SN + tc] = fast_tanh(s);
            } else {
                float s = wsm[76];
#pragma unroll
                for (int u = 0; u < 8; ++u) s += hidC[rr * 8 + u] * wsm[68 + u];
                out[OFF_CONF + b * SN + tc] = fast_sig(s);
            }
        }
        if (t < SN) {
            *(u64*)&zin[lr * ZINS + 64 + lc8]     = v0;
            *(u64*)&zin[lr * ZINS + 64 + lc8 + 4] = v1;
        }
        __syncthreads();  // S6
    }
}

extern "C" void kernel_launch(void* const* d_in, const int* in_sizes, int n_in,
                              void* d_out, int out_size, void* d_ws, size_t ws_size,
                              hipStream_t stream) {
    (void)in_sizes; (void)n_in; (void)out_size; (void)ws_size;
    const float* p[29];
    for (int i = 0; i < 29; ++i) p[i] = (const float*)d_in[i];
    unsigned int* flags = (unsigned int*)d_ws;
    u64* hbuf = (u64*)((char*)d_ws + FLAG_BYTES);
    hipMemsetAsync(d_ws, 0, FLAG_BYTES, stream);
    hipLaunchKernelGGL(lh_scan_kernel, dim3(128), dim3(512), 0, stream,
        p[0], p[1], p[2], p[3], p[4], p[5], p[6], p[7], p[8], p[9], p[10], p[11], p[12],
        p[13], p[14], p[15], p[16], p[17], p[18], p[19], p[20], p[21], p[22], p[23],
        p[24], p[25], p[26], p[27], p[28], (float*)d_out, flags, hbuf);
}